// Round 6
// baseline (586.610 us; speedup 1.0000x reference)
//
#include <hip/hip_runtime.h>
#include <hip/hip_bf16.h>
#include <math.h>

// ---------------------------------------------------------------------------
// TransformerBlock: B=8 T=1024 C=1024 H=16 d=64, bf16 MFMA compute, fp32 acc.
// R6: gemm_res -> split-K=2 + XCD-group swizzle + fp32 atomic epilogue
//     (4 blocks/CU, A-tile pinned to one XCD); gemm_big gets the swizzle too.
// ---------------------------------------------------------------------------

#define DEVI __device__ __forceinline__

typedef __attribute__((ext_vector_type(4))) float floatx4;
typedef __attribute__((ext_vector_type(16))) float floatx16;
typedef __attribute__((ext_vector_type(8))) short shortx8;   // 8 bf16 = 4 VGPRs

DEVI ushort f2b(float f) {
    __hip_bfloat16 h = __float2bfloat16(f);
    return __builtin_bit_cast(ushort, h);
}

DEVI void gl_lds16(const ushort* g, ushort* l) {
    // 16B direct global->LDS. LDS dest = wave-uniform base + lane*16.
    __builtin_amdgcn_global_load_lds(
        (const __attribute__((address_space(1))) void*)g,
        (__attribute__((address_space(3))) void*)l, 16, 0, 0);
}

// tanh-form GeLU: |err| vs erf-GeLU ~3e-3 — far under the bf16 threshold.
DEVI float gelu_f(float v) {
    const float u0 = 0.7978845608f * v * (1.0f + 0.044715f * v * v);
    const float u  = fminf(fmaxf(u0, -15.0f), 15.0f);
    const float e  = exp2f(u * 2.885390082f);      // e^{2u}
    const float th = 1.0f - 2.0f / (e + 1.0f);     // tanh(u)
    return 0.5f * v * (1.0f + th);
}

// ---------------------------------------------------------------------------
// Fused transpose of the four 1024x1024 weights (z picks the matrix).
// ---------------------------------------------------------------------------
__global__ void transp4_kernel(const float* __restrict__ s0, const float* __restrict__ s1,
                               const float* __restrict__ s2, const float* __restrict__ s3,
                               ushort* __restrict__ d0, ushort* __restrict__ d1,
                               ushort* __restrict__ d2, ushort* __restrict__ d3) {
    const int z = blockIdx.z;
    const float* src = (z == 0) ? s0 : (z == 1) ? s1 : (z == 2) ? s2 : s3;
    ushort*      dst = (z == 0) ? d0 : (z == 1) ? d1 : (z == 2) ? d2 : d3;
    __shared__ float tile[32][33];
    const int c0 = blockIdx.x * 32, r0 = blockIdx.y * 32;
    const int tx = threadIdx.x, ty = threadIdx.y;   // 32 x 8
#pragma unroll
    for (int i = 0; i < 32; i += 8)
        tile[ty + i][tx] = src[(size_t)(r0 + ty + i) * 1024 + c0 + tx];
    __syncthreads();
#pragma unroll
    for (int i = 0; i < 32; i += 8)
        dst[(size_t)(c0 + ty + i) * 1024 + r0 + tx] = f2b(tile[tx][ty + i]);
}

__global__ void transp_kernel(const float* __restrict__ src,
                              ushort* __restrict__ dst, int R, int C) {
    __shared__ float tile[32][33];
    const int c0 = blockIdx.x * 32, r0 = blockIdx.y * 32;
    const int tx = threadIdx.x, ty = threadIdx.y;   // 32 x 8
#pragma unroll
    for (int i = 0; i < 32; i += 8)
        tile[ty + i][tx] = src[(size_t)(r0 + ty + i) * C + c0 + tx];
    __syncthreads();
#pragma unroll
    for (int i = 0; i < 32; i += 8)
        dst[(size_t)(c0 + ty + i) * R + r0 + tx] = f2b(tile[tx][ty + i]);
}

// ---------------------------------------------------------------------------
// LayerNorm over C=1024, one block (256 thr) per token. fp32 in, bf16 out.
// ---------------------------------------------------------------------------
__global__ __launch_bounds__(256)
void ln_kernel(const float* __restrict__ x, const float* __restrict__ w,
               const float* __restrict__ b, ushort* __restrict__ out) {
    __shared__ float red[8];
    const int m = blockIdx.x;
    const int tid = threadIdx.x;
    const float4 xv = *(const float4*)&x[(size_t)m * 1024 + tid * 4];
    float s  = xv.x + xv.y + xv.z + xv.w;
    float s2 = xv.x * xv.x + xv.y * xv.y + xv.z * xv.z + xv.w * xv.w;
#pragma unroll
    for (int o = 32; o >= 1; o >>= 1) {
        s  += __shfl_xor(s, o, 64);
        s2 += __shfl_xor(s2, o, 64);
    }
    const int wv_ = tid >> 6;
    if ((tid & 63) == 0) { red[wv_] = s; red[4 + wv_] = s2; }
    __syncthreads();
    s  = red[0] + red[1] + red[2] + red[3];
    s2 = red[4] + red[5] + red[6] + red[7];
    const float mu   = s * (1.0f / 1024.0f);
    const float var  = s2 * (1.0f / 1024.0f) - mu * mu;
    const float rstd = rsqrtf(var + 1e-5f);
    const float4 wv = *(const float4*)&w[tid * 4];
    const float4 bv = *(const float4*)&b[tid * 4];
    ushort o4[4];
    o4[0] = f2b((xv.x - mu) * rstd * wv.x + bv.x);
    o4[1] = f2b((xv.y - mu) * rstd * wv.y + bv.y);
    o4[2] = f2b((xv.z - mu) * rstd * wv.z + bv.z);
    o4[3] = f2b((xv.w - mu) * rstd * wv.w + bv.w);
    *(uint2*)&out[(size_t)m * 1024 + tid * 4] = *(uint2*)o4;
}

// ---------------------------------------------------------------------------
// BIG GEMM: 256(M) x 128(N) tile, BK=64. 4 waves, each 128x64 via 4x2 of
// mfma_32x32x16_bf16. 1-D grid, XCD-swizzled so blocks sharing an A-tile
// (same m0) have ids == c (mod 8) -> one XCD's L2 under round-robin dispatch.
//   MODE 1: fused QKV  (Q/K heads layout, V^T via wave-parity LDS transpose)
//   MODE 3: bf16 out = gelu(acc + bias)
// ---------------------------------------------------------------------------
template <int MODE>
__global__ __launch_bounds__(256, 2)
void gemm_big(const ushort* __restrict__ A, const ushort* __restrict__ Bt,
              const float* __restrict__ biasQ, const float* __restrict__ biasK,
              const float* __restrict__ biasV,
              void* __restrict__ out, void* __restrict__ out2, void* __restrict__ out3,
              int N, int K, int NXT) {
    __shared__ ushort lds[(256 + 128) * 64];   // 48 KB: sA 256x64, sB 128x64
    ushort* sA = lds;
    ushort* sB = lds + 256 * 64;

    const int tid  = threadIdx.x;
    const int lane = tid & 63;
    const int wave = tid >> 6;
    const int l31  = lane & 31;
    const int half = lane >> 5;
    const int wm   = (wave & 1) * 128;
    const int wn   = (wave >> 1) * 64;

    // XCD-group swizzle: ids == c (mod 8) share m0
    const int id = blockIdx.x;
    const int c  = id & 7;
    const int q  = id >> 3;
    const int jx = q % NXT;
    const int gg = q / NXT;
    const int m0 = (gg * 8 + c) * 256;
    const int n0 = jx * 128;

    floatx16 acc[4][2] = {};

    const int lrow = lane >> 3;          // 0..7
    const int scb  = (lane & 7) ^ lrow;  // swizzled SOURCE col-block
    const ushort* Ag = A  + (size_t)(m0 + wave * 8 + lrow) * K + scb * 8;
    const ushort* Bg = Bt + (size_t)(n0 + wave * 8 + lrow) * K + scb * 8;

    for (int k0 = 0; k0 < K; k0 += 64) {
        __syncthreads();
#pragma unroll
        for (int p = 0; p < 8; ++p)
            gl_lds16(Ag + (size_t)(p * 32) * K + k0, sA + (p * 32 + wave * 8) * 64);
#pragma unroll
        for (int p = 0; p < 4; ++p)
            gl_lds16(Bg + (size_t)(p * 32) * K + k0, sB + (p * 32 + wave * 8) * 64);
        __syncthreads();
#pragma unroll
        for (int ks = 0; ks < 4; ++ks) {
            const int cx = ks * 2 + half;
            shortx8 af[4], bf[2];
#pragma unroll
            for (int i = 0; i < 4; ++i) {
                const int r = wm + i * 32 + l31;
                af[i] = *(const shortx8*)&sA[r * 64 + (cx ^ (r & 7)) * 8];
            }
#pragma unroll
            for (int j = 0; j < 2; ++j) {
                const int r = wn + j * 32 + l31;
                bf[j] = *(const shortx8*)&sB[r * 64 + (cx ^ (r & 7)) * 8];
            }
#pragma unroll
            for (int i = 0; i < 4; ++i)
#pragma unroll
                for (int j = 0; j < 2; ++j)
                    acc[i][j] = __builtin_amdgcn_mfma_f32_32x32x16_bf16(
                        af[i], bf[j], acc[i][j], 0, 0, 0);
        }
    }

    if constexpr (MODE == 1) {
        const int mat = n0 >> 10;   // block-uniform (128 | 1024)
        if (mat < 2) {
            const float* bp = (mat == 0) ? biasQ : biasK;
            ushort* dst = (mat == 0) ? (ushort*)out : (ushort*)out2;
            const int bb = m0 >> 10;
            const int tbase = m0 & 1023;
#pragma unroll
            for (int i = 0; i < 4; ++i)
#pragma unroll
                for (int j = 0; j < 2; ++j) {
                    const int cn = (n0 & 1023) + wn + j * 32 + l31;
                    const float bv = bp[cn];
                    const int h = cn >> 6, dd = cn & 63;
#pragma unroll
                    for (int reg = 0; reg < 16; ++reg) {
                        const int t = tbase + wm + i * 32 + (reg & 3) + 8 * (reg >> 2) + 4 * half;
                        dst[((size_t)(bb * 16 + h) * 1024 + t) * 64 + dd] =
                            f2b(acc[i][j][reg] + bv);
                    }
                }
        } else {
            // V: wave-parity halves through a 128x136 LDS transpose tile
            ushort* T = lds;
            const int vb = n0 - 2048;
            const int bb = m0 >> 10;
#pragma unroll
            for (int hf = 0; hf < 2; ++hf) {
                __syncthreads();
                if ((wave & 1) == hf) {
#pragma unroll
                    for (int i = 0; i < 4; ++i)
#pragma unroll
                        for (int j = 0; j < 2; ++j) {
                            const int dim = wn + j * 32 + l31;   // 0..127 local
                            const float bv = biasV[vb + dim];
#pragma unroll
                            for (int rq = 0; rq < 4; ++rq) {
                                const int tloc = i * 32 + 8 * rq + 4 * half;
                                ushort pk[4];
#pragma unroll
                                for (int e = 0; e < 4; ++e)
                                    pk[e] = f2b(acc[i][j][rq * 4 + e] + bv);
                                *(uint2*)&T[dim * 136 + tloc] = *(uint2*)pk;
                            }
                        }
                }
                __syncthreads();
#pragma unroll
                for (int pass = 0; pass < 8; ++pass) {
                    const int row = pass * 16 + (tid >> 4);   // dim-local 0..127
                    const int cb  = (tid & 15) * 8;           // t-local chunk
                    const uint4 val = *(const uint4*)&T[row * 136 + cb];
                    const int dd = vb + row;
                    const int h = dd >> 6, dl = dd & 63;
                    const int t = (m0 & 1023) + hf * 128 + cb;
                    *(uint4*)&((ushort*)out3)[((size_t)(bb * 16 + h) * 64 + dl) * 1024 + t] = val;
                }
            }
        }
    } else {   // MODE 3: gelu
#pragma unroll
        for (int i = 0; i < 4; ++i)
#pragma unroll
            for (int j = 0; j < 2; ++j) {
                const int gn = n0 + wn + j * 32 + l31;
                const float bv = biasQ[gn];
#pragma unroll
                for (int reg = 0; reg < 16; ++reg) {
                    const int gm = m0 + wm + i * 32 + (reg & 3) + 8 * (reg >> 2) + 4 * half;
                    const float v = acc[i][j][reg] + bv;
                    ((ushort*)out)[(size_t)gm * N + gn] = f2b(gelu_f(v));
                }
            }
    }
}

// ---------------------------------------------------------------------------
// Residual GEMM, split-K=2 + atomic accumulate.
// 128x128 tile. Grid = 1024 1-D blocks: 8(n) x 64(m) x 2(k-half),
// XCD-swizzled so the 8 n-blocks AND both k-halves of an m-tile share an XCD.
// out must be pre-loaded (memset-0 for Wo path) — blocks atomically add
// acc (+ bias + optional resid in the k-half-0 block).
//   FOLD_RESID=1: k-half-0 adds bias[gn] + resid[gm][gn]   (Wo: resid = x)
//   FOLD_RESID=0: k-half-0 adds bias[gn] only              (FFN2: out holds x2)
// ---------------------------------------------------------------------------
template <int FOLD_RESID>
__global__ __launch_bounds__(256)
void gemm_res(const ushort* __restrict__ A, const ushort* __restrict__ Bt,
              const float* __restrict__ bias, float* __restrict__ out,
              const float* __restrict__ resid, int N, int K) {
    __shared__ ushort lds[128 * 64 * 2];
    ushort* sA = lds;
    ushort* sB = lds + 128 * 64;

    const int tid  = threadIdx.x;
    const int lane = tid & 63;
    const int wave = tid >> 6;
    const int l31  = lane & 31;
    const int half = lane >> 5;
    const int wm   = (wave & 1) * 64;
    const int wn   = (wave >> 1) * 64;

    // swizzle: mk = g*8+c -> (m-tile, k-half); 8 n-blocks (j) share (mk, XCD c)
    const int id = blockIdx.x;
    const int c  = id & 7;
    const int q  = id >> 3;
    const int jx = q & 7;
    const int g  = q >> 3;
    const int mk = g * 8 + c;
    const int m0 = (mk & 63) * 128;
    const int kh = mk >> 6;
    const int n0 = jx * 128;
    const int Kh = K >> 1;
    const int kend = kh * Kh + Kh;

    floatx16 acc[2][2] = {};

    const int lrow = lane >> 3;
    const int scb  = (lane & 7) ^ lrow;
    const ushort* Ag = A  + (size_t)(m0 + wave * 8 + lrow) * K + scb * 8;
    const ushort* Bg = Bt + (size_t)(n0 + wave * 8 + lrow) * K + scb * 8;

    for (int k0 = kh * Kh; k0 < kend; k0 += 64) {
        __syncthreads();
#pragma unroll
        for (int p = 0; p < 4; ++p) {
            gl_lds16(Ag + (size_t)(p * 32) * K + k0, sA + (p * 32 + wave * 8) * 64);
            gl_lds16(Bg + (size_t)(p * 32) * K + k0, sB + (p * 32 + wave * 8) * 64);
        }
        __syncthreads();
#pragma unroll
        for (int ks = 0; ks < 4; ++ks) {
            const int cx = ks * 2 + half;
            shortx8 af[2], bf[2];
#pragma unroll
            for (int i = 0; i < 2; ++i) {
                const int r = wm + i * 32 + l31;
                af[i] = *(const shortx8*)&sA[r * 64 + (cx ^ (r & 7)) * 8];
            }
#pragma unroll
            for (int j = 0; j < 2; ++j) {
                const int r = wn + j * 32 + l31;
                bf[j] = *(const shortx8*)&sB[r * 64 + (cx ^ (r & 7)) * 8];
            }
#pragma unroll
            for (int i = 0; i < 2; ++i)
#pragma unroll
                for (int j = 0; j < 2; ++j)
                    acc[i][j] = __builtin_amdgcn_mfma_f32_32x32x16_bf16(
                        af[i], bf[j], acc[i][j], 0, 0, 0);
        }
    }
    const bool lead = (kh == 0);
#pragma unroll
    for (int i = 0; i < 2; ++i)
#pragma unroll
        for (int j = 0; j < 2; ++j) {
            const int gn = n0 + wn + j * 32 + l31;
            const float bv = bias[gn];
#pragma unroll
            for (int reg = 0; reg < 16; ++reg) {
                const int gm = m0 + wm + i * 32 + (reg & 3) + 8 * (reg >> 2) + 4 * half;
                float v = acc[i][j][reg];
                if (lead) {
                    v += bv;
                    if constexpr (FOLD_RESID)
                        v += resid[(size_t)gm * N + gn];
                }
                unsafeAtomicAdd(&out[(size_t)gm * N + gn], v);
            }
        }
    (void)resid;
}

// ---------------------------------------------------------------------------
// Flash-style causal attention, LDS-staged (unchanged from R4).
// blockIdx: bh in low 7 bits -> same-bh q-tiles already share an XCD (mod 8).
// ---------------------------------------------------------------------------
__global__ __launch_bounds__(256)
void attn_kernel(const ushort* __restrict__ Q, const ushort* __restrict__ Kk,
                 const ushort* __restrict__ Vt, ushort* __restrict__ ctx) {
    __shared__ ushort sK[64 * 64];
    __shared__ ushort sV[64 * 64];     // V^T tile: [d][64 kv-cols]
    __shared__ ushort sP[4][16 * 72];

    const int tid  = threadIdx.x;
    const int lane = tid & 63;
    const int wave = tid >> 6;
    const int quad = lane >> 4;
    const int l15  = lane & 15;

    const int qb = 15 - (blockIdx.x >> 7);   // descending workload
    const int bh = blockIdx.x & 127;
    const size_t base = (size_t)bh << 16;    // bh*1024*64
    const int bb = bh >> 4, h = bh & 15;

    const int lrow = lane >> 3;
    const int scb  = (lane & 7) ^ lrow;
    const ushort* Kg = Kk + base + (size_t)(wave * 8 + lrow) * 64 + scb * 8;
    const ushort* Vg = Vt + base + (size_t)(wave * 8 + lrow) * 1024 + scb * 8;

    const int qrow = qb * 64 + wave * 16 + l15;
    const shortx8 qf0 = *(const shortx8*)&Q[base + (size_t)qrow * 64 + quad * 8];
    const shortx8 qf1 = *(const shortx8*)&Q[base + (size_t)qrow * 64 + 32 + quad * 8];

    const float SC = 0.125f * 1.44269504f;   // exp2-domain scaling

    float mstate[4], lstate[4];
    floatx4 oacc[4] = {};
#pragma unroll
    for (int r = 0; r < 4; ++r) { mstate[r] = -__builtin_inff(); lstate[r] = 0.0f; }

    for (int kt = 0; kt <= qb; ++kt) {
        __syncthreads();
#pragma unroll
        for (int p = 0; p < 2; ++p) {
            gl_lds16(Kg + (size_t)kt * 4096 + (size_t)p * 2048,
                     sK + (p * 32 + wave * 8) * 64);
            gl_lds16(Vg + (size_t)kt * 64 + (size_t)p * 32 * 1024,
                     sV + (p * 32 + wave * 8) * 64);
        }
        __syncthreads();

        floatx4 s[4];
#pragma unroll
        for (int nt = 0; nt < 4; ++nt) {
            const int r = nt * 16 + l15;
            const int c0 = quad ^ (r & 7);
            const int c1 = (4 + quad) ^ (r & 7);
            const shortx8 kf0 = *(const shortx8*)&sK[r * 64 + c0 * 8];
            const shortx8 kf1 = *(const shortx8*)&sK[r * 64 + c1 * 8];
            floatx4 z = {};
            z = __builtin_amdgcn_mfma_f32_16x16x32_bf16(qf0, kf0, z, 0, 0, 0);
            z = __builtin_amdgcn_mfma_f32_16x16x32_bf16(qf1, kf1, z, 0, 0, 0);
            s[nt] = z;
        }
#pragma unroll
        for (int nt = 0; nt < 4; ++nt)
#pragma unroll
            for (int r = 0; r < 4; ++r) {
                float sv = s[nt][r] * SC;
                if (kt == qb) {
                    const int col = nt * 16 + l15;
                    const int row = wave * 16 + quad * 4 + r;
                    if (col > row) sv = -__builtin_inff();
                }
                s[nt][r] = sv;
            }
        float mnew[4], alpha[4];
#pragma unroll
        for (int r = 0; r < 4; ++r) {
            float mt = fmaxf(fmaxf(s[0][r], s[1][r]), fmaxf(s[2][r], s[3][r]));
#pragma unroll
            for (int o = 8; o >= 1; o >>= 1) mt = fmaxf(mt, __shfl_xor(mt, o, 64));
            mnew[r]  = fmaxf(mstate[r], mt);
            alpha[r] = exp2f(mstate[r] - mnew[r]);
            mstate[r] = mnew[r];
        }
#pragma unroll
        for (int r = 0; r < 4; ++r) {
            float rs = 0.0f;
#pragma unroll
            for (int nt = 0; nt < 4; ++nt) {
                const float p = exp2f(s[nt][r] - mnew[r]);
                s[nt][r] = p;
                rs += p;
            }
#pragma unroll
            for (int o = 8; o >= 1; o >>= 1) rs += __shfl_xor(rs, o, 64);
            lstate[r] = alpha[r] * lstate[r] + rs;
#pragma unroll
            for (int dt = 0; dt < 4; ++dt) oacc[dt][r] *= alpha[r];
        }
#pragma unroll
        for (int nt = 0; nt < 4; ++nt)
#pragma unroll
            for (int r = 0; r < 4; ++r)
                sP[wave][(quad * 4 + r) * 72 + nt * 16 + l15] = f2b(s[nt][r]);
        __asm__ volatile("s_waitcnt lgkmcnt(0)" ::: "memory");
        const shortx8 pf0 = *(const shortx8*)&sP[wave][l15 * 72 + quad * 8];
        const shortx8 pf1 = *(const shortx8*)&sP[wave][l15 * 72 + 32 + quad * 8];
#pragma unroll
        for (int dt = 0; dt < 4; ++dt) {
            const int r = dt * 16 + l15;
            const int c0 = quad ^ (r & 7);
            const int c1 = (4 + quad) ^ (r & 7);
            const shortx8 v0 = *(const shortx8*)&sV[r * 64 + c0 * 8];
            const shortx8 v1 = *(const shortx8*)&sV[r * 64 + c1 * 8];
            oacc[dt] = __builtin_amdgcn_mfma_f32_16x16x32_bf16(pf0, v0, oacc[dt], 0, 0, 0);
            oacc[dt] = __builtin_amdgcn_mfma_f32_16x16x32_bf16(pf1, v1, oacc[dt], 0, 0, 0);
        }
    }
#pragma unroll
    for (int dt = 0; dt < 4; ++dt)
#pragma unroll
        for (int r = 0; r < 4; ++r) {
            const int t = qb * 64 + wave * 16 + quad * 4 + r;
            const int dim = dt * 16 + l15;
            const float v = oacc[dt][r] / lstate[r];
            ctx[(size_t)(bb * 1024 + t) * 1024 + h * 64 + dim] = f2b(v);
        }
}

// ---------------------------------------------------------------------------
// Launch
// ---------------------------------------------------------------------------
extern "C" void kernel_launch(void* const* d_in, const int* in_sizes, int n_in,
                              void* d_out, int out_size, void* d_ws, size_t ws_size,
                              hipStream_t stream) {
    const float* x    = (const float*)d_in[0];
    const float* ln1w = (const float*)d_in[2];
    const float* ln1b = (const float*)d_in[3];
    const float* ln2w = (const float*)d_in[4];
    const float* ln2b = (const float*)d_in[5];
    const float* wq   = (const float*)d_in[6];
    const float* bq   = (const float*)d_in[7];
    const float* wk   = (const float*)d_in[8];
    const float* bk   = (const float*)d_in[9];
    const float* wv   = (const float*)d_in[10];
    const float* bv   = (const float*)d_in[11];
    const float* wo   = (const float*)d_in[12];
    const float* bo   = (const float*)d_in[13];
    const float* w1   = (const float*)d_in[14];
    const float* b1   = (const float*)d_in[15];
    const float* w2   = (const float*)d_in[16];
    const float* b2   = (const float*)d_in[17];

    char* ws = (char*)d_ws;
    const size_t MB = 1024 * 1024;
    ushort* WQKVT = (ushort*)(ws + 0 * MB);     // [3072][1024] bf16 (wq|wk|wv ^T)
    ushort* WOT   = (ushort*)(ws + 6 * MB);     // [1024][1024]
    ushort* W1T   = (ushort*)(ws + 8 * MB);     // [4096][1024]
    ushort* W2T   = (ushort*)(ws + 16 * MB);    // [1024][4096]
    ushort* H1    = (ushort*)(ws + 24 * MB);    // [8192][1024]; H2 overlays later
    ushort* H2    = H1;
    ushort* Qb    = (ushort*)(ws + 40 * MB);    // [128][1024][64]
    ushort* Kb    = (ushort*)(ws + 56 * MB);    // [128][1024][64]
    ushort* Vbt   = (ushort*)(ws + 72 * MB);    // [128][64][1024]
    ushort* FF1   = (ushort*)(ws + 40 * MB);    // [8192][4096] overlays Q,K,V (dead)
    ushort* CTX   = (ushort*)(ws + 104 * MB);   // [8192][1024]

    float* xout = (float*)d_out;                // x2 lives here, then final out

    // zero the accumulation target for the atomic split-K Wo epilogue
    hipMemsetAsync(xout, 0, (size_t)8192 * 1024 * sizeof(float), stream);

    const dim3 tb(32, 8);
    transp4_kernel<<<dim3(32, 32, 4), tb, 0, stream>>>(
        wq, wk, wv, wo,
        WQKVT, WQKVT + 1024 * 1024, WQKVT + 2048 * 1024, WOT);
    transp_kernel<<<dim3(128, 32), tb, 0, stream>>>(w1, W1T, 1024, 4096);
    transp_kernel<<<dim3(32, 128), tb, 0, stream>>>(w2, W2T, 4096, 1024);

    ln_kernel<<<8192, 256, 0, stream>>>(x, ln1w, ln1b, H1);

    gemm_big<1><<<768, 256, 0, stream>>>(H1, WQKVT, bq, bk, bv,
                                         Qb, Kb, Vbt, 3072, 1024, 24);

    attn_kernel<<<2048, 256, 0, stream>>>(Qb, Kb, Vbt, CTX);

    // xout = 0 + (ctx@wo + bo + x)   [split-K atomic]
    gemm_res<1><<<1024, 256, 0, stream>>>(CTX, WOT, bo, xout, x, 1024, 1024);

    ln_kernel<<<8192, 256, 0, stream>>>(xout, ln2w, ln2b, H2);

    gemm_big<3><<<1024, 256, 0, stream>>>(H2, W1T, b1, nullptr, nullptr,
                                          FF1, nullptr, nullptr, 4096, 1024, 32);

    // xout += ff1@w2 + b2            [split-K atomic, xout holds x2]
    gemm_res<0><<<1024, 256, 0, stream>>>(FF1, W2T, b2, xout, nullptr, 1024, 4096);

    (void)in_sizes; (void)n_in; (void)out_size; (void)ws_size;
}